// Round 1
// baseline (2248.417 us; speedup 1.0000x reference)
//
#include <hip/hip_runtime.h>

typedef unsigned long long u64;
typedef unsigned int u32;

#define LOGB 22
#define NBUCKETS (1u << LOGB)
#define SCAN_T 256
#define SCAN_E 8
#define SCAN_CHUNK (SCAN_T * SCAN_E)   // 2048

// ---------------- hash + bucket histogram ----------------
__global__ void k_hash_hist(const int* __restrict__ coords, u64* __restrict__ h,
                            u32* __restrict__ hist, int N) {
    int i = blockIdx.x * blockDim.x + threadIdx.x;
    if (i >= N) return;
    u64 hv = 14695981039346656037ull;
    const u64 P = 1099511628211ull;
#pragma unroll
    for (int j = 0; j < 4; j++) {
        hv *= P;
        hv ^= (u64)(long long)coords[i * 4 + j];
    }
    h[i] = hv;
    atomicAdd(&hist[(u32)(hv >> (64 - LOGB))], 1u);
}

// ---------------- generic 2-level scan ----------------
// Level-1: per-chunk scan (in place). EXCL -> exclusive, else inclusive.
// Writes chunk totals to sums.
template <bool EXCL>
__global__ void k_scan_chunks(u32* data, int n, u32* sums) {
    __shared__ u32 s[SCAN_T];
    int tid = threadIdx.x;
    int base = blockIdx.x * SCAN_CHUNK;
    int idx0 = base + tid * SCAN_E;
    u32 v[SCAN_E], o[SCAN_E];
    u32 run = 0;
#pragma unroll
    for (int k = 0; k < SCAN_E; k++) {
        int idx = idx0 + k;
        u32 x = (idx < n) ? data[idx] : 0u;
        o[k] = x;
        run += x;
        v[k] = run;  // inclusive within thread
    }
    s[tid] = run;
    __syncthreads();
    for (int off = 1; off < SCAN_T; off <<= 1) {
        u32 t = (tid >= off) ? s[tid - off] : 0u;
        __syncthreads();
        s[tid] += t;
        __syncthreads();
    }
    u32 tbase = s[tid] - run;  // exclusive prefix of this thread
#pragma unroll
    for (int k = 0; k < SCAN_E; k++) {
        int idx = idx0 + k;
        if (idx < n) data[idx] = tbase + v[k] - (EXCL ? o[k] : 0u);
    }
    if (tid == SCAN_T - 1 && sums) sums[blockIdx.x] = s[SCAN_T - 1];
}

// Level-2: single block exclusive scan in place (n <= SCAN_CHUNK).
__global__ void k_scan_single(u32* data, int n) {
    __shared__ u32 s[SCAN_T];
    int tid = threadIdx.x;
    int idx0 = tid * SCAN_E;
    u32 v[SCAN_E], o[SCAN_E];
    u32 run = 0;
#pragma unroll
    for (int k = 0; k < SCAN_E; k++) {
        int idx = idx0 + k;
        u32 x = (idx < n) ? data[idx] : 0u;
        o[k] = x;
        run += x;
        v[k] = run;
    }
    s[tid] = run;
    __syncthreads();
    for (int off = 1; off < SCAN_T; off <<= 1) {
        u32 t = (tid >= off) ? s[tid - off] : 0u;
        __syncthreads();
        s[tid] += t;
        __syncthreads();
    }
    u32 tbase = s[tid] - run;
#pragma unroll
    for (int k = 0; k < SCAN_E; k++) {
        int idx = idx0 + k;
        if (idx < n) data[idx] = tbase + v[k] - o[k];
    }
}

// Level-3: add chunk offsets.
__global__ void k_scan_add(u32* data, int n, const u32* __restrict__ sums) {
    int i = blockIdx.x * blockDim.x + threadIdx.x;
    if (i >= n) return;
    data[i] += sums[i / SCAN_CHUNK];
}

// ---------------- scatter into buckets ----------------
__global__ void k_scatter(const u64* __restrict__ h, u32* __restrict__ offs,
                          u64* __restrict__ key, int* __restrict__ idxs, int N) {
    int i = blockIdx.x * blockDim.x + threadIdx.x;
    if (i >= N) return;
    u64 hv = h[i];
    u32 b = (u32)(hv >> (64 - LOGB));
    u32 pos = atomicAdd(&offs[b], 1u);
    key[pos] = hv;
    idxs[pos] = i;
}

// ---------------- within-bucket insertion sort (tiny buckets) ----------------
__global__ void k_bucket_sort(const u32* __restrict__ offs, u64* key, int* idxs, int B) {
    int b = blockIdx.x * blockDim.x + threadIdx.x;
    if (b >= B) return;
    int end = (int)offs[b];                  // after scatter: end of bucket b
    int start = b ? (int)offs[b - 1] : 0;    // end of previous bucket
    if (end - start < 2) return;
    for (int j = start + 1; j < end; j++) {
        u64 kj = key[j];
        int ij = idxs[j];
        int k = j - 1;
        while (k >= start && (key[k] > kj || (key[k] == kj && idxs[k] > ij))) {
            key[k + 1] = key[k];
            idxs[k + 1] = idxs[k];
            k--;
        }
        key[k + 1] = kj;
        idxs[k + 1] = ij;
    }
}

// ---------------- first-occurrence flags ----------------
__global__ void k_first(const u64* __restrict__ key, u32* __restrict__ gid, int N) {
    int i = blockIdx.x * blockDim.x + threadIdx.x;
    if (i >= N) return;
    gid[i] = (i == 0 || key[i] != key[i - 1]) ? 1u : 0u;
}

// ---------------- finalize all outputs ----------------
__global__ void k_finalize(const u32* __restrict__ gid, const int* __restrict__ idxs,
                           const int* __restrict__ coords, const float* __restrict__ feats,
                           float* __restrict__ vox_feats, float* __restrict__ vox_coords,
                           float* __restrict__ v2p, float* __restrict__ nvox, int N, int C) {
    int i = blockIdx.x * blockDim.x + threadIdx.x;
    if (i >= N) return;
    u32 gi = gid[i];
    int g = (int)gi - 1;
    v2p[idxs[i]] = (float)g;
    bool first = (i == 0) || (gid[i - 1] != gi);
    if (first) {
        int p = idxs[i];
#pragma unroll
        for (int c = 0; c < 4; c++) vox_coords[(size_t)g * 4 + c] = (float)coords[p * 4 + c];
        float acc[16];
        for (int c = 0; c < C; c++) acc[c] = 0.0f;
        int j = i;
        int cnt = 0;
        while (j < N && gid[j] == gi) {
            const float* f = &feats[(size_t)idxs[j] * C];
            for (int c = 0; c < C; c++) acc[c] += f[c];
            cnt++;
            j++;
        }
        float fc = (float)cnt;
        for (int c = 0; c < C; c++) vox_feats[(size_t)g * C + c] = acc[c] / fc;
    }
    if (i == N - 1) nvox[0] = (float)gi;
}

extern "C" void kernel_launch(void* const* d_in, const int* in_sizes, int n_in,
                              void* d_out, int out_size, void* d_ws, size_t ws_size,
                              hipStream_t stream) {
    const int* coords = (const int*)d_in[0];
    const float* feats = (const float*)d_in[1];
    int N = in_sizes[0] / 4;
    int C = in_sizes[1] / N;  // 16

    float* out = (float*)d_out;
    float* vox_feats = out;                          // N*C
    float* vox_coords = out + (size_t)N * C;         // N*4
    float* v2p = vox_coords + (size_t)N * 4;         // N
    float* nvox = v2p + (size_t)N;                   // 1

    char* w = (char*)d_ws;
    u64* h = (u64*)w;        w += (size_t)N * 8;
    u64* key = (u64*)w;      w += (size_t)N * 8;
    int* idxs = (int*)w;     w += (size_t)N * 4;
    u32* gid = (u32*)w;      w += (size_t)N * 4;
    u32* offs = (u32*)w;     w += (size_t)NBUCKETS * 4;
    u32* sums = (u32*)w;     w += (size_t)SCAN_CHUNK * 4;

    hipMemsetAsync(offs, 0, (size_t)NBUCKETS * 4, stream);
    hipMemsetAsync(d_out, 0, (size_t)out_size * 4, stream);

    int blocks = (N + 255) / 256;

    k_hash_hist<<<blocks, 256, 0, stream>>>(coords, h, offs, N);

    // exclusive scan over NBUCKETS (in place)
    int bchunks = NBUCKETS / SCAN_CHUNK;  // 2048 (exact)
    k_scan_chunks<true><<<bchunks, SCAN_T, 0, stream>>>(offs, (int)NBUCKETS, sums);
    k_scan_single<<<1, SCAN_T, 0, stream>>>(sums, bchunks);
    k_scan_add<<<(NBUCKETS + 255) / 256, 256, 0, stream>>>(offs, (int)NBUCKETS, sums);

    k_scatter<<<blocks, 256, 0, stream>>>(h, offs, key, idxs, N);
    k_bucket_sort<<<(NBUCKETS + 255) / 256, 256, 0, stream>>>(offs, key, idxs, (int)NBUCKETS);

    k_first<<<blocks, 256, 0, stream>>>(key, gid, N);

    // inclusive scan over N (in place)
    int nchunks = (N + SCAN_CHUNK - 1) / SCAN_CHUNK;
    k_scan_chunks<false><<<nchunks, SCAN_T, 0, stream>>>(gid, N, sums);
    k_scan_single<<<1, SCAN_T, 0, stream>>>(sums, nchunks);
    k_scan_add<<<blocks, 256, 0, stream>>>(gid, N, sums);

    k_finalize<<<blocks, 256, 0, stream>>>(gid, idxs, coords, feats, vox_feats, vox_coords,
                                           v2p, nvox, N, C);
}